// Round 12
// baseline (76.088 us; speedup 1.0000x reference)
//
#include <hip/hip_runtime.h>
#include <stdint.h>

#define E2V     600000
#define NNODES  50000
#define UCNT    500
#define DE      100
#define DOUT    100
#define NB      16
#define KTOT    3328      // 3200 (G) + 100 (x/root) + 1 (bias) + 27 pad
#define MROWS   512
#define HASHN   2048      // LDS hash (node -> last u), 500 keys
#define CAP     96        // per-slot edge cap (mean ~12)
#define NF      74        // filter blocks, 8192 edges each
#define TRB     832       // 104 k-tiles * 4 j-tiles * 2 branches
#define NKS     13        // K splits of 256 (8 MFMA chunks each)

using short8 = __attribute__((ext_vector_type(8))) short;
using f32x4  = __attribute__((ext_vector_type(4))) float;

static constexpr size_t align256(size_t x){ return (x + 255) & ~size_t(255); }
static constexpr size_t OFF_SCNT = 0;                                         // 512 i32 (memset 0)
static constexpr size_t OFF_IHEA = align256(OFF_SCNT + MROWS*4);              // 512 i32
static constexpr size_t OFF_INEX = OFF_IHEA + MROWS*4;                        // 512 i32
static constexpr size_t OFF_ELIS = align256(OFF_INEX + MROWS*4);              // 512*96 i32
static constexpr size_t OFF_ESRC = align256(OFF_ELIS + (size_t)MROWS*CAP*4);  // 512*96 i16
static constexpr size_t OFF_GM   = align256(OFF_ESRC + (size_t)MROWS*CAP*2);  // 512*3328 bf16
static constexpr size_t OFF_GS   = OFF_GM + (size_t)MROWS*KTOT*2;
static constexpr size_t OFF_BTM  = align256(OFF_GS + (size_t)MROWS*KTOT*2);   // 100*3328 bf16
static constexpr size_t OFF_BTS  = OFF_BTM + (size_t)DOUT*KTOT*2;
static constexpr size_t OFF_P    = align256(OFF_BTS + (size_t)DOUT*KTOT*2);   // 2*13*512*100 f32

__device__ __forceinline__ unsigned short f2b(float f){
    uint32_t u = __float_as_uint(f);
    uint32_t r = (u + 0x7FFFu + ((u >> 16) & 1u)) >> 16;
    return (unsigned short)r;
}

__device__ __forceinline__ uint32_t hh(int key){
    return (((uint32_t)key * 2654435761u) >> 16) & (HASHN - 1);
}
__device__ __forceinline__ void hins(int* hk, int* hv, int key, int val){
    uint32_t idx = hh(key);
    while (true){
        int k = hk[idx];
        if (k == key){ atomicMax(&hv[idx], val); return; }
        if (k == -1){
            int old = atomicCAS(&hk[idx], -1, key);
            if (old == -1 || old == key){ atomicMax(&hv[idx], val); return; }
        }
        idx = (idx + 1) & (HASHN - 1);
    }
}
__device__ __forceinline__ int hlook(const int* hk, const int* hv, int key){
    uint32_t idx = hh(key);
    while (true){
        int k = hk[idx];
        if (k == key) return hv[idx];
        if (k == -1)  return -1;
        idx = (idx + 1) & (HASHN - 1);
    }
}

__device__ __forceinline__ float bt_src(const float* __restrict__ basis,
                                        const float* __restrict__ root,
                                        const float* __restrict__ bias,
                                        int k, int j){
    if (j >= 100) return 0.f;
    if (k < 3200) return basis[k*100 + j];
    if (k < 3300) return root[(k-3200)*100 + j];
    if (k == 3300) return bias[j];
    return 0.f;
}

// ---- K1: [0..73] edge filter (8192 edges each) -> direct per-slot lists (+src lookup);
//          [74..905] Bt transpose; [906] inverse chains. scnt pre-zeroed by memset. ----
__global__ __launch_bounds__(256) void k1(
        const int* __restrict__ unseen_index, const int* __restrict__ eidx,
        int* __restrict__ scnt, int* __restrict__ elist, short* __restrict__ esrc,
        int* __restrict__ ihead, int* __restrict__ inext,
        const float* __restrict__ bm, const float* __restrict__ bs,
        const float* __restrict__ rm, const float* __restrict__ rs,
        const float* __restrict__ qm, const float* __restrict__ qs,
        unsigned short* __restrict__ btm, unsigned short* __restrict__ bts){
    __shared__ int hk[HASHN], hv[HASHN];
    __shared__ float tile[32][33];
    __shared__ int sIH[MROWS];
    int bx = blockIdx.x, tid = threadIdx.x;

    if (bx < NF){
        for (int i = tid; i < HASHN; i += 256){ hk[i] = -1; hv[i] = -1; }
        __syncthreads();
        for (int u = tid; u < UCNT; u += 256) hins(hk, hv, unseen_index[u], u);
        __syncthreads();
        for (int r = 0; r < 8; ++r){
            int e0 = bx*8192 + (r*256 + tid)*4;
            if (e0 >= E2V) break;
            int4 d = *(const int4*)(eidx + E2V + e0);
            #pragma unroll
            for (int j = 0; j < 4; ++j){
                int dn = (j==0) ? d.x : (j==1) ? d.y : (j==2) ? d.z : d.w;
                int s = hlook(hk, hv, dn);
                if (s >= 0){
                    int e = e0 + j;
                    int srcp = hlook(hk, hv, eidx[e]);
                    int pos = atomicAdd(&scnt[s], 1);
                    if (pos < CAP){
                        elist[s*CAP + pos] = e;
                        esrc[s*CAP + pos] = (short)srcp;
                    }
                }
            }
        }
        return;
    }
    if (bx < NF + TRB){
        int b2 = bx - NF;
        int kt = b2 % 104, jt = (b2 / 104) & 3, br = b2 / 416;
        const float* basis = br ? bs : bm;
        const float* root  = br ? rs : rm;
        const float* bias  = br ? qs : qm;
        unsigned short* bt = br ? bts : btm;
        int k0 = kt*32, j0 = jt*32;
        int tx = tid & 31, ty = tid >> 5;
        for (int r = ty; r < 32; r += 8)
            tile[r][tx] = bt_src(basis, root, bias, k0 + r, j0 + tx);
        __syncthreads();
        for (int r = ty; r < 32; r += 8){
            int j = j0 + r;
            if (j < 100) bt[(size_t)j*KTOT + k0 + tx] = f2b(tile[tx][r]);
        }
        return;
    }
    // chain block
    for (int i = tid; i < HASHN; i += 256){ hk[i] = -1; hv[i] = -1; }
    for (int i = tid; i < MROWS; i += 256) sIH[i] = -1;
    __syncthreads();
    for (int u = tid; u < UCNT; u += 256) hins(hk, hv, unseen_index[u], u);
    __syncthreads();
    for (int u = tid; u < UCNT; u += 256){
        int slot = hlook(hk, hv, unseen_index[u]);
        inext[u] = atomicExch(&sIH[slot], u);
    }
    __syncthreads();
    for (int i = tid; i < MROWS; i += 256) ihead[i] = sIH[i];
}

// ---- K2: build G rows (no hash, no scan): G[slot] = [ sum/cnt | x | 1 | 0 ] bf16 ----
__global__ __launch_bounds__(256) void k_g(
        const int* __restrict__ scnt, const int* __restrict__ elist,
        const short* __restrict__ esrc,
        const int* __restrict__ eidx,
        const int* __restrict__ etype, const int* __restrict__ rel_index,
        const int* __restrict__ node_id,
        const float* __restrict__ ent, const float* __restrict__ unseen,
        const float* __restrict__ rel,
        const float* __restrict__ am, const float* __restrict__ as_,
        unsigned short* __restrict__ Gm, unsigned short* __restrict__ Gs){
    int slot = blockIdx.x;
    int tid  = threadIdx.x;
    int nT = scnt[slot];
    int nE = nT > CAP ? CAP : nT;
    __shared__ __align__(16) float sM[8][200];
    __shared__ __align__(16) float sAm[8][16], sAs[8][16];
    __shared__ const float* sPX[8];
    __shared__ const float* sPR[8];
    __shared__ int sT[8];

    float gm[16], gs[16];
    #pragma unroll
    for (int b = 0; b < NB; ++b){ gm[b] = 0.f; gs[b] = 0.f; }

    for (int c0 = 0; c0 < nE; c0 += 8){
        int kc = nE - c0; if (kc > 8) kc = 8;
        if (tid < kc){
            int e = elist[slot*CAP + c0 + tid];
            sT[tid] = etype[e];
            int srcp = esrc[slot*CAP + c0 + tid];
            sPX[tid] = (srcp >= 0) ? unseen + (size_t)srcp*DE
                                   : ent + (size_t)node_id[eidx[e]]*DE;
            sPR[tid] = rel + (size_t)rel_index[e]*DE;
        }
        __syncthreads();
        for (int q = tid; q < kc*50; q += 256){
            int eL = q / 50, s = q % 50;
            const float* base = (s < 25) ? sPX[eL] : sPR[eL];
            int off = (s < 25) ? s*4 : (s-25)*4;
            float4 v = *(const float4*)(base + off);
            int kb = (s < 25) ? s*4 : (s-25)*4 + 100;
            *(float4*)&sM[eL][kb] = v;
        }
        if (tid < kc*16){
            int eL = tid >> 4, b = tid & 15;
            int t = sT[eL];
            sAm[eL][b] = am[t*NB + b];
            sAs[eL][b] = as_[t*NB + b];
        }
        __syncthreads();
        if (tid < 200){
            for (int e = 0; e < kc; ++e){
                float mk = sM[e][tid];
                const float4* pa = (const float4*)&sAm[e][0];
                const float4* ps = (const float4*)&sAs[e][0];
                #pragma unroll
                for (int q = 0; q < 4; ++q){
                    float4 va = pa[q], vs = ps[q];
                    gm[q*4+0] += va.x*mk; gm[q*4+1] += va.y*mk;
                    gm[q*4+2] += va.z*mk; gm[q*4+3] += va.w*mk;
                    gs[q*4+0] += vs.x*mk; gs[q*4+1] += vs.y*mk;
                    gs[q*4+2] += vs.z*mk; gs[q*4+3] += vs.w*mk;
                }
            }
        }
        __syncthreads();
    }
    size_t row = (size_t)slot * KTOT;
    float inv = 1.f / fmaxf((float)nT, 1.f);
    if (tid < 200){
        #pragma unroll
        for (int b = 0; b < NB; ++b){
            Gm[row + b*200 + tid] = f2b(gm[b] * inv);
            Gs[row + b*200 + tid] = f2b(gs[b] * inv);
        }
    }
    if (tid < 100){
        float xv = (slot < UCNT) ? unseen[(size_t)slot*DE + tid] : 0.f;
        unsigned short h = f2b(xv);
        Gm[row + 3200 + tid] = h; Gs[row + 3200 + tid] = h;
    } else if (tid == 100){
        Gm[row + 3300] = f2b(1.f); Gs[row + 3300] = f2b(1.f);
    } else if (tid > 100 && tid < 128){
        Gm[row + 3200 + tid] = 0; Gs[row + 3200 + tid] = 0;   // 3301..3327
    }
}

// ---- K3: P[br][ks] = G_aug(ks-chunk) @ B_aug. Block = (br, m32, ks13);
//      7 waves = 7 j-tiles; 2 m16 sub-jobs share each B-fragment; coalesced
//      partial stores, no atomics, no LDS. ----
__global__ __launch_bounds__(448) void k_gemm(
        const unsigned short* __restrict__ Gm, const unsigned short* __restrict__ Gs,
        const unsigned short* __restrict__ Btm, const unsigned short* __restrict__ Bts,
        float* __restrict__ P){
    int bid = blockIdx.x;                 // 0..415
    int br  = bid / 208;
    int rem = bid % 208;
    int m32 = rem & 15;                   // 16 M-tiles of 32 rows
    int ks  = rem >> 4;                   // 0..12, 256 K-elems each
    int jt  = threadIdx.x >> 6;           // wave = j-tile 0..6
    int lane = threadIdx.x & 63;
    const unsigned short* A  = br ? Gs : Gm;
    const unsigned short* Bt = br ? Bts : Btm;
    int rowa = lane & 15, ko = (lane >> 4) * 8;
    int j0 = (jt == 6) ? 84 : jt*16;      // overlap trick, guard col>=96
    int col = j0 + rowa;
    size_t kbase = (size_t)ks*256 + ko;
    const unsigned short* bp  = Bt + (size_t)col*KTOT + kbase;
    const unsigned short* ap0 = A  + (size_t)(m32*32 + rowa)*KTOT + kbase;
    const unsigned short* ap1 = ap0 + (size_t)16*KTOT;
    f32x4 acc0 = {0.f,0.f,0.f,0.f}, acc1 = {0.f,0.f,0.f,0.f};
    #pragma unroll
    for (int kc = 0; kc < 8; ++kc){
        short8 bv = *(const short8*)(bp + kc*32);
        acc0 = __builtin_amdgcn_mfma_f32_16x16x32_bf16(*(const short8*)(ap0 + kc*32), bv, acc0, 0, 0, 0);
        acc1 = __builtin_amdgcn_mfma_f32_16x16x32_bf16(*(const short8*)(ap1 + kc*32), bv, acc1, 0, 0, 0);
    }
    if (jt < 6 || col >= 96){
        float* Pb = P + (size_t)(br*NKS + ks)*MROWS*100;
        #pragma unroll
        for (int mi = 0; mi < 2; ++mi){
            f32x4 acc = mi ? acc1 : acc0;
            int r0 = m32*32 + mi*16 + (lane >> 4)*4;
            #pragma unroll
            for (int r = 0; r < 4; ++r)
                Pb[(size_t)(r0 + r)*100 + col] = acc[r];
        }
    }
}

// ---- K4: out = sum_ks P, scattered to the 3 output blocks via chains ----
__global__ __launch_bounds__(128) void k_out(
        const float* __restrict__ P,
        const int* __restrict__ ihead, const int* __restrict__ inext,
        float* __restrict__ out){
    int slot = blockIdx.x;
    int tid  = threadIdx.x;
    if (tid >= 100) return;
    float mu = 0.f, sg = 0.f;
    #pragma unroll
    for (int ks = 0; ks < NKS; ++ks){
        mu += P[((size_t)ks*MROWS + slot)*100 + tid];
        sg += P[((size_t)(NKS + ks)*MROWS + slot)*100 + tid];
    }
    int u = ihead[slot];
    while (u >= 0){
        out[(size_t)u*100 + tid] = mu;
        out[(size_t)(UCNT + u)*100 + tid] = mu;
        out[(size_t)(2*UCNT + u)*100 + tid] = sg;
        u = inext[u];
    }
}

extern "C" void kernel_launch(void* const* d_in, const int* in_sizes, int n_in,
                              void* d_out, int out_size, void* d_ws, size_t ws_size,
                              hipStream_t stream){
    const float* ent        = (const float*)d_in[0];
    const float* rel_table  = (const float*)d_in[1];
    const float* unseen_emb = (const float*)d_in[2];
    const float* att_mu     = (const float*)d_in[3];
    const float* basis_mu   = (const float*)d_in[4];
    const float* root_mu    = (const float*)d_in[5];
    const float* bias_mu    = (const float*)d_in[6];
    const float* att_sig    = (const float*)d_in[7];
    const float* basis_sig  = (const float*)d_in[8];
    const float* root_sig   = (const float*)d_in[9];
    const float* bias_sig   = (const float*)d_in[10];
    const int* node_id      = (const int*)d_in[11];
    const int* edge_index   = (const int*)d_in[12];
    const int* edge_type    = (const int*)d_in[13];
    const int* rel_index    = (const int*)d_in[14];
    const int* unseen_index = (const int*)d_in[15];
    float* out = (float*)d_out;
    char* ws = (char*)d_ws;

    int* scnt   = (int*)(ws + OFF_SCNT);
    int* ihead  = (int*)(ws + OFF_IHEA);
    int* inext  = (int*)(ws + OFF_INEX);
    int* elist  = (int*)(ws + OFF_ELIS);
    short* esrc = (short*)(ws + OFF_ESRC);
    unsigned short* Gm  = (unsigned short*)(ws + OFF_GM);
    unsigned short* Gs  = (unsigned short*)(ws + OFF_GS);
    unsigned short* Btm = (unsigned short*)(ws + OFF_BTM);
    unsigned short* Bts = (unsigned short*)(ws + OFF_BTS);
    float* P = (float*)(ws + OFF_P);

    hipMemsetAsync(scnt, 0, MROWS*4, stream);
    k1<<<NF + TRB + 1, 256, 0, stream>>>(unseen_index, edge_index,
        scnt, elist, esrc, ihead, inext,
        basis_mu, basis_sig, root_mu, root_sig, bias_mu, bias_sig, Btm, Bts);
    k_g<<<MROWS, 256, 0, stream>>>(scnt, elist, esrc, edge_index, edge_type,
        rel_index, node_id, ent, unseen_emb, rel_table, att_mu, att_sig, Gm, Gs);
    k_gemm<<<416, 448, 0, stream>>>(Gm, Gs, Btm, Bts, P);
    k_out<<<MROWS, 128, 0, stream>>>(P, ihead, inext, out);
}

// Round 13
// 52.142 us; speedup vs baseline: 1.4592x; 1.4592x over previous
//
#include <hip/hip_runtime.h>
#include <stdint.h>

#define E2V     600000
#define NNODES  50000
#define UCNT    500
#define DE      100
#define DOUT    100
#define NB      16
#define KTOT    3328      // 3200 (G) + 100 (x/root) + 1 (bias) + 27 pad
#define MROWS   512
#define HASHN   2048      // LDS hash (node -> last u), 500 keys
#define HCAP    64        // per-filter-block hit cap (mean ~10)
#define NREG    586       // ceil(600000/1024) filter blocks/regions
#define ECAP    96        // per-slot edge cap (mean ~12)
#define TRB     832       // 104 k-tiles * 4 j-tiles * 2 branches
#define NKS     13        // K splits of 256 (8 MFMA chunks each)

using short8 = __attribute__((ext_vector_type(8))) short;
using f32x4  = __attribute__((ext_vector_type(4))) float;

static constexpr size_t align256(size_t x){ return (x + 255) & ~size_t(255); }
static constexpr size_t OFF_HCNT = 0;                                         // 586 i32
static constexpr size_t OFF_IHEA = align256(OFF_HCNT + NREG*4);               // 512 i32
static constexpr size_t OFF_INEX = OFF_IHEA + MROWS*4;                        // 512 i32
static constexpr size_t OFF_HBUF = align256(OFF_INEX + MROWS*4);              // 586*64 u32
static constexpr size_t OFF_GM   = align256(OFF_HBUF + (size_t)NREG*HCAP*4);  // 512*3328 bf16
static constexpr size_t OFF_GS   = OFF_GM + (size_t)MROWS*KTOT*2;
static constexpr size_t OFF_BTM  = align256(OFF_GS + (size_t)MROWS*KTOT*2);   // 100*3328 bf16
static constexpr size_t OFF_BTS  = OFF_BTM + (size_t)DOUT*KTOT*2;
static constexpr size_t OFF_P    = align256(OFF_BTS + (size_t)DOUT*KTOT*2);   // 2*13*512*100 f32

__device__ __forceinline__ unsigned short f2b(float f){
    uint32_t u = __float_as_uint(f);
    uint32_t r = (u + 0x7FFFu + ((u >> 16) & 1u)) >> 16;
    return (unsigned short)r;
}

__device__ __forceinline__ uint32_t hh(int key){
    return (((uint32_t)key * 2654435761u) >> 16) & (HASHN - 1);
}
// LDS hash: insert (key, val) with last-wins (atomicMax on val)
__device__ __forceinline__ void hins(int* hk, int* hv, int key, int val){
    uint32_t idx = hh(key);
    while (true){
        int k = hk[idx];
        if (k == key){ atomicMax(&hv[idx], val); return; }
        if (k == -1){
            int old = atomicCAS(&hk[idx], -1, key);
            if (old == -1 || old == key){ atomicMax(&hv[idx], val); return; }
        }
        idx = (idx + 1) & (HASHN - 1);
    }
}
__device__ __forceinline__ int hlook(const int* hk, const int* hv, int key){
    uint32_t idx = hh(key);
    while (true){
        int k = hk[idx];
        if (k == key) return hv[idx];
        if (k == -1)  return -1;
        idx = (idx + 1) & (HASHN - 1);
    }
}

__device__ __forceinline__ float bt_src(const float* __restrict__ basis,
                                        const float* __restrict__ root,
                                        const float* __restrict__ bias,
                                        int k, int j){
    if (j >= 100) return 0.f;
    if (k < 3200) return basis[k*100 + j];
    if (k < 3300) return root[(k-3200)*100 + j];
    if (k == 3300) return bias[j];
    return 0.f;
}

// ---- K1: [0..585] edge filter -> per-block hit regions; [586..1417] Bt transpose;
//          [1418] inverse chains.  All roles fully independent (no init deps). ----
__global__ __launch_bounds__(256) void k1(
        const int* __restrict__ unseen_index, const int* __restrict__ eidx,
        int* __restrict__ hcnt, uint32_t* __restrict__ hbuf,
        int* __restrict__ ihead, int* __restrict__ inext,
        const float* __restrict__ bm, const float* __restrict__ bs,
        const float* __restrict__ rm, const float* __restrict__ rs,
        const float* __restrict__ qm, const float* __restrict__ qs,
        unsigned short* __restrict__ btm, unsigned short* __restrict__ bts){
    __shared__ int hk[HASHN], hv[HASHN];
    __shared__ float tile[32][33];
    __shared__ uint32_t sHit[HCAP];
    __shared__ int sN, sIH[MROWS];
    int bx = blockIdx.x, tid = threadIdx.x;

    if (bx < NREG){
        for (int i = tid; i < HASHN; i += 256){ hk[i] = -1; hv[i] = -1; }
        if (tid == 0) sN = 0;
        __syncthreads();
        for (int u = tid; u < UCNT; u += 256) hins(hk, hv, unseen_index[u], u);
        __syncthreads();
        int e0 = bx*1024 + tid*4;
        if (e0 < E2V){
            int4 d = *(const int4*)(eidx + E2V + e0);
            int s;
            s = hlook(hk, hv, d.x); if (s >= 0){ int p = atomicAdd(&sN,1); if (p < HCAP) sHit[p] = ((uint32_t)s<<21)|(uint32_t)(e0);   }
            s = hlook(hk, hv, d.y); if (s >= 0){ int p = atomicAdd(&sN,1); if (p < HCAP) sHit[p] = ((uint32_t)s<<21)|(uint32_t)(e0+1); }
            s = hlook(hk, hv, d.z); if (s >= 0){ int p = atomicAdd(&sN,1); if (p < HCAP) sHit[p] = ((uint32_t)s<<21)|(uint32_t)(e0+2); }
            s = hlook(hk, hv, d.w); if (s >= 0){ int p = atomicAdd(&sN,1); if (p < HCAP) sHit[p] = ((uint32_t)s<<21)|(uint32_t)(e0+3); }
        }
        __syncthreads();
        int n = sN < HCAP ? sN : HCAP;
        if (tid == 0) hcnt[bx] = n;
        if (tid < n) hbuf[bx*HCAP + tid] = sHit[tid];
        return;
    }
    if (bx < NREG + TRB){
        int b2 = bx - NREG;
        int kt = b2 % 104, jt = (b2 / 104) & 3, br = b2 / 416;
        const float* basis = br ? bs : bm;
        const float* root  = br ? rs : rm;
        const float* bias  = br ? qs : qm;
        unsigned short* bt = br ? bts : btm;
        int k0 = kt*32, j0 = jt*32;
        int tx = tid & 31, ty = tid >> 5;
        for (int r = ty; r < 32; r += 8)
            tile[r][tx] = bt_src(basis, root, bias, k0 + r, j0 + tx);
        __syncthreads();
        for (int r = ty; r < 32; r += 8){
            int j = j0 + r;
            if (j < 100) bt[(size_t)j*KTOT + k0 + tx] = f2b(tile[tx][r]);
        }
        return;
    }
    // chain block
    for (int i = tid; i < HASHN; i += 256){ hk[i] = -1; hv[i] = -1; }
    for (int i = tid; i < MROWS; i += 256) sIH[i] = -1;
    __syncthreads();
    for (int u = tid; u < UCNT; u += 256) hins(hk, hv, unseen_index[u], u);
    __syncthreads();
    for (int u = tid; u < UCNT; u += 256){
        int slot = hlook(hk, hv, unseen_index[u]);
        inext[u] = atomicExch(&sIH[slot], u);
    }
    __syncthreads();
    for (int i = tid; i < MROWS; i += 256) ihead[i] = sIH[i];
}

// ---- K2: build G rows: G[slot] = [ (1/cnt)*sum_e att[t_e]⊗m_e | x | 1 | 0 ] bf16 ----
__global__ __launch_bounds__(256) void k_g(
        const int* __restrict__ hcnt, const uint32_t* __restrict__ hbuf,
        const int* __restrict__ unseen_index,
        const int* __restrict__ eidx,
        const int* __restrict__ etype, const int* __restrict__ rel_index,
        const int* __restrict__ node_id,
        const float* __restrict__ ent, const float* __restrict__ unseen,
        const float* __restrict__ rel,
        const float* __restrict__ am, const float* __restrict__ as_,
        unsigned short* __restrict__ Gm, unsigned short* __restrict__ Gs){
    int slot = blockIdx.x;
    int tid  = threadIdx.x;
    __shared__ int hk[HASHN], hv[HASHN];
    __shared__ int sEdge[ECAP], sNE;
    __shared__ __align__(16) float sM[8][200];
    __shared__ __align__(16) float sAm[8][16], sAs[8][16];
    __shared__ const float* sPX[8];
    __shared__ const float* sPR[8];
    __shared__ int sT[8];

    for (int i = tid; i < HASHN; i += 256){ hk[i] = -1; hv[i] = -1; }
    if (tid == 0) sNE = 0;
    __syncthreads();
    for (int u = tid; u < UCNT; u += 256) hins(hk, hv, unseen_index[u], u);
    __syncthreads();
    // collect this slot's edges from the hit regions
    for (int r = tid; r < NREG; r += 256){
        int c = hcnt[r];
        for (int i = 0; i < c; ++i){
            uint32_t h = hbuf[r*HCAP + i];
            if ((int)(h >> 21) == slot){
                int p = atomicAdd(&sNE, 1);
                if (p < ECAP) sEdge[p] = (int)(h & 0x1FFFFFu);
            }
        }
    }
    __syncthreads();
    int nT = sNE;
    int nE = nT > ECAP ? ECAP : nT;

    float gm[16], gs[16];
    #pragma unroll
    for (int b = 0; b < NB; ++b){ gm[b] = 0.f; gs[b] = 0.f; }

    for (int c0 = 0; c0 < nE; c0 += 8){
        int kc = nE - c0; if (kc > 8) kc = 8;
        if (tid < kc){
            int e = sEdge[c0 + tid];
            sT[tid] = etype[e];
            int s = eidx[e];
            int p = hlook(hk, hv, s);
            sPX[tid] = (p >= 0) ? unseen + (size_t)p*DE : ent + (size_t)node_id[s]*DE;
            sPR[tid] = rel + (size_t)rel_index[e]*DE;
        }
        __syncthreads();
        for (int q = tid; q < kc*50; q += 256){
            int eL = q / 50, s = q % 50;
            const float* base = (s < 25) ? sPX[eL] : sPR[eL];
            int off = (s < 25) ? s*4 : (s-25)*4;
            float4 v = *(const float4*)(base + off);
            int kb = (s < 25) ? s*4 : (s-25)*4 + 100;
            *(float4*)&sM[eL][kb] = v;
        }
        if (tid < kc*16){
            int eL = tid >> 4, b = tid & 15;
            int t = sT[eL];
            sAm[eL][b] = am[t*NB + b];
            sAs[eL][b] = as_[t*NB + b];
        }
        __syncthreads();
        if (tid < 200){
            for (int e = 0; e < kc; ++e){
                float mk = sM[e][tid];
                const float4* pa = (const float4*)&sAm[e][0];
                const float4* ps = (const float4*)&sAs[e][0];
                #pragma unroll
                for (int q = 0; q < 4; ++q){
                    float4 va = pa[q], vs = ps[q];
                    gm[q*4+0] += va.x*mk; gm[q*4+1] += va.y*mk;
                    gm[q*4+2] += va.z*mk; gm[q*4+3] += va.w*mk;
                    gs[q*4+0] += vs.x*mk; gs[q*4+1] += vs.y*mk;
                    gs[q*4+2] += vs.z*mk; gs[q*4+3] += vs.w*mk;
                }
            }
        }
        __syncthreads();
    }
    size_t row = (size_t)slot * KTOT;
    float inv = 1.f / fmaxf((float)nT, 1.f);
    if (tid < 200){
        #pragma unroll
        for (int b = 0; b < NB; ++b){
            Gm[row + b*200 + tid] = f2b(gm[b] * inv);
            Gs[row + b*200 + tid] = f2b(gs[b] * inv);
        }
    }
    if (tid < 100){
        float xv = (slot < UCNT) ? unseen[(size_t)slot*DE + tid] : 0.f;
        unsigned short h = f2b(xv);
        Gm[row + 3200 + tid] = h; Gs[row + 3200 + tid] = h;
    } else if (tid == 100){
        Gm[row + 3300] = f2b(1.f); Gs[row + 3300] = f2b(1.f);
    } else if (tid > 100 && tid < 128){
        Gm[row + 3200 + tid] = 0; Gs[row + 3200 + tid] = 0;   // 3301..3327
    }
}

// ---- K3: P[br][ks] = G_aug(ks-chunk) @ B_aug. Block = (br, m32, ks13);
//      7 waves = 7 j-tiles; 2 m16 sub-jobs share each B-fragment; coalesced
//      partial stores, no atomics, no LDS. ----
__global__ __launch_bounds__(448) void k_gemm(
        const unsigned short* __restrict__ Gm, const unsigned short* __restrict__ Gs,
        const unsigned short* __restrict__ Btm, const unsigned short* __restrict__ Bts,
        float* __restrict__ P){
    int bid = blockIdx.x;                 // 0..415
    int br  = bid / 208;
    int rem = bid % 208;
    int m32 = rem & 15;                   // 16 M-tiles of 32 rows
    int ks  = rem >> 4;                   // 0..12, 256 K-elems each
    int jt  = threadIdx.x >> 6;           // wave = j-tile 0..6
    int lane = threadIdx.x & 63;
    const unsigned short* A  = br ? Gs : Gm;
    const unsigned short* Bt = br ? Bts : Btm;
    int rowa = lane & 15, ko = (lane >> 4) * 8;
    int j0 = (jt == 6) ? 84 : jt*16;      // overlap trick, guard col>=96
    int col = j0 + rowa;
    size_t kbase = (size_t)ks*256 + ko;
    const unsigned short* bp  = Bt + (size_t)col*KTOT + kbase;
    const unsigned short* ap0 = A  + (size_t)(m32*32 + rowa)*KTOT + kbase;
    const unsigned short* ap1 = ap0 + (size_t)16*KTOT;
    f32x4 acc0 = {0.f,0.f,0.f,0.f}, acc1 = {0.f,0.f,0.f,0.f};
    #pragma unroll
    for (int kc = 0; kc < 8; ++kc){
        short8 bv = *(const short8*)(bp + kc*32);
        acc0 = __builtin_amdgcn_mfma_f32_16x16x32_bf16(*(const short8*)(ap0 + kc*32), bv, acc0, 0, 0, 0);
        acc1 = __builtin_amdgcn_mfma_f32_16x16x32_bf16(*(const short8*)(ap1 + kc*32), bv, acc1, 0, 0, 0);
    }
    if (jt < 6 || col >= 96){
        float* Pb = P + (size_t)(br*NKS + ks)*MROWS*100;
        #pragma unroll
        for (int mi = 0; mi < 2; ++mi){
            f32x4 acc = mi ? acc1 : acc0;
            int r0 = m32*32 + mi*16 + (lane >> 4)*4;
            #pragma unroll
            for (int r = 0; r < 4; ++r)
                Pb[(size_t)(r0 + r)*100 + col] = acc[r];
        }
    }
}

// ---- K4: out = sum_ks P, scattered to the 3 output blocks via chains ----
__global__ __launch_bounds__(128) void k_out(
        const float* __restrict__ P,
        const int* __restrict__ ihead, const int* __restrict__ inext,
        float* __restrict__ out){
    int slot = blockIdx.x;
    int tid  = threadIdx.x;
    if (tid >= 100) return;
    float mu = 0.f, sg = 0.f;
    #pragma unroll
    for (int ks = 0; ks < NKS; ++ks){
        mu += P[((size_t)ks*MROWS + slot)*100 + tid];
        sg += P[((size_t)(NKS + ks)*MROWS + slot)*100 + tid];
    }
    int u = ihead[slot];
    while (u >= 0){
        out[(size_t)u*100 + tid] = mu;
        out[(size_t)(UCNT + u)*100 + tid] = mu;
        out[(size_t)(2*UCNT + u)*100 + tid] = sg;
        u = inext[u];
    }
}

extern "C" void kernel_launch(void* const* d_in, const int* in_sizes, int n_in,
                              void* d_out, int out_size, void* d_ws, size_t ws_size,
                              hipStream_t stream){
    const float* ent        = (const float*)d_in[0];
    const float* rel_table  = (const float*)d_in[1];
    const float* unseen_emb = (const float*)d_in[2];
    const float* att_mu     = (const float*)d_in[3];
    const float* basis_mu   = (const float*)d_in[4];
    const float* root_mu    = (const float*)d_in[5];
    const float* bias_mu    = (const float*)d_in[6];
    const float* att_sig    = (const float*)d_in[7];
    const float* basis_sig  = (const float*)d_in[8];
    const float* root_sig   = (const float*)d_in[9];
    const float* bias_sig   = (const float*)d_in[10];
    const int* node_id      = (const int*)d_in[11];
    const int* edge_index   = (const int*)d_in[12];
    const int* edge_type    = (const int*)d_in[13];
    const int* rel_index    = (const int*)d_in[14];
    const int* unseen_index = (const int*)d_in[15];
    float* out = (float*)d_out;
    char* ws = (char*)d_ws;

    int* hcnt       = (int*)(ws + OFF_HCNT);
    int* ihead      = (int*)(ws + OFF_IHEA);
    int* inext      = (int*)(ws + OFF_INEX);
    uint32_t* hbuf  = (uint32_t*)(ws + OFF_HBUF);
    unsigned short* Gm  = (unsigned short*)(ws + OFF_GM);
    unsigned short* Gs  = (unsigned short*)(ws + OFF_GS);
    unsigned short* Btm = (unsigned short*)(ws + OFF_BTM);
    unsigned short* Bts = (unsigned short*)(ws + OFF_BTS);
    float* P = (float*)(ws + OFF_P);

    k1<<<NREG + TRB + 1, 256, 0, stream>>>(unseen_index, edge_index,
        hcnt, hbuf, ihead, inext,
        basis_mu, basis_sig, root_mu, root_sig, bias_mu, bias_sig, Btm, Bts);
    k_g<<<MROWS, 256, 0, stream>>>(hcnt, hbuf, unseen_index, edge_index, edge_type,
        rel_index, node_id, ent, unseen_emb, rel_table, att_mu, att_sig, Gm, Gs);
    k_gemm<<<416, 448, 0, stream>>>(Gm, Gs, Btm, Bts, P);
    k_out<<<MROWS, 128, 0, stream>>>(P, ihead, inext, out);
}

// Round 14
// 48.744 us; speedup vs baseline: 1.5610x; 1.0697x over previous
//
#include <hip/hip_runtime.h>
#include <stdint.h>

#define E2V     600000
#define NNODES  50000
#define UCNT    500
#define DE      100
#define DOUT    100
#define NB      16
#define KTOT    3328      // 3200 (G) + 100 (x/root) + 1 (bias) + 27 pad
#define MROWS   512
#define HASHN   2048      // LDS hash (node -> last u), 500 keys
#define HCAP    64        // per-filter-block hit cap (mean ~10)
#define NREG    586       // ceil(600000/1024) filter blocks/regions
#define ECAP    96        // per-slot edge cap (mean ~12)
#define TRB     832       // 104 k-tiles * 4 j-tiles * 2 branches

using short8 = __attribute__((ext_vector_type(8))) short;
using f32x4  = __attribute__((ext_vector_type(4))) float;

static constexpr size_t align256(size_t x){ return (x + 255) & ~size_t(255); }
static constexpr size_t OFF_HCNT = 0;                                         // 586 i32
static constexpr size_t OFF_IHEA = align256(OFF_HCNT + NREG*4);               // 512 i32
static constexpr size_t OFF_INEX = OFF_IHEA + MROWS*4;                        // 512 i32
static constexpr size_t OFF_HBUF = align256(OFF_INEX + MROWS*4);              // 586*64 u64
static constexpr size_t OFF_GM   = align256(OFF_HBUF + (size_t)NREG*HCAP*8);  // 512*3328 bf16
static constexpr size_t OFF_GS   = OFF_GM + (size_t)MROWS*KTOT*2;
static constexpr size_t OFF_BTM  = align256(OFF_GS + (size_t)MROWS*KTOT*2);   // 100*3328 bf16
static constexpr size_t OFF_BTS  = OFF_BTM + (size_t)DOUT*KTOT*2;             // total ~8.3 MB

__device__ __forceinline__ unsigned short f2b(float f){
    uint32_t u = __float_as_uint(f);
    uint32_t r = (u + 0x7FFFu + ((u >> 16) & 1u)) >> 16;
    return (unsigned short)r;
}

__device__ __forceinline__ uint32_t hh(int key){
    return (((uint32_t)key * 2654435761u) >> 16) & (HASHN - 1);
}
// LDS hash: insert (key, val) with last-wins (atomicMax on val)
__device__ __forceinline__ void hins(int* hk, int* hv, int key, int val){
    uint32_t idx = hh(key);
    while (true){
        int k = hk[idx];
        if (k == key){ atomicMax(&hv[idx], val); return; }
        if (k == -1){
            int old = atomicCAS(&hk[idx], -1, key);
            if (old == -1 || old == key){ atomicMax(&hv[idx], val); return; }
        }
        idx = (idx + 1) & (HASHN - 1);
    }
}
__device__ __forceinline__ int hlook(const int* hk, const int* hv, int key){
    uint32_t idx = hh(key);
    while (true){
        int k = hk[idx];
        if (k == key) return hv[idx];
        if (k == -1)  return -1;
        idx = (idx + 1) & (HASHN - 1);
    }
}

__device__ __forceinline__ float bt_src(const float* __restrict__ basis,
                                        const float* __restrict__ root,
                                        const float* __restrict__ bias,
                                        int k, int j){
    if (j >= 100) return 0.f;
    if (k < 3200) return basis[k*100 + j];
    if (k < 3300) return root[(k-3200)*100 + j];
    if (k == 3300) return bias[j];
    return 0.f;
}

// ---- K1: [0..585] edge filter -> per-block hit regions (slot+src resolved);
//          [586..1417] Bt transpose; [1418] inverse chains. No init deps. ----
__global__ __launch_bounds__(256) void k1(
        const int* __restrict__ unseen_index, const int* __restrict__ eidx,
        int* __restrict__ hcnt, uint64_t* __restrict__ hbuf,
        int* __restrict__ ihead, int* __restrict__ inext,
        const float* __restrict__ bm, const float* __restrict__ bs,
        const float* __restrict__ rm, const float* __restrict__ rs,
        const float* __restrict__ qm, const float* __restrict__ qs,
        unsigned short* __restrict__ btm, unsigned short* __restrict__ bts){
    __shared__ int hk[HASHN], hv[HASHN];
    __shared__ float tile[32][33];
    __shared__ uint64_t sHit[HCAP];
    __shared__ int sN, sIH[MROWS];
    int bx = blockIdx.x, tid = threadIdx.x;

    if (bx < NREG){
        for (int i = tid; i < HASHN; i += 256){ hk[i] = -1; hv[i] = -1; }
        if (tid == 0) sN = 0;
        __syncthreads();
        for (int u = tid; u < UCNT; u += 256) hins(hk, hv, unseen_index[u], u);
        __syncthreads();
        int e0 = bx*1024 + tid*4;
        if (e0 < E2V){
            int4 d = *(const int4*)(eidx + E2V + e0);
            #pragma unroll
            for (int j = 0; j < 4; ++j){
                int dn = (j==0) ? d.x : (j==1) ? d.y : (j==2) ? d.z : d.w;
                int s = hlook(hk, hv, dn);
                if (s >= 0){
                    int e = e0 + j;
                    int srcp = hlook(hk, hv, eidx[e]);   // src membership (last-wins pos)
                    int p = atomicAdd(&sN, 1);
                    if (p < HCAP)
                        sHit[p] = ((uint64_t)(uint32_t)(srcp + 1) << 32)
                                | ((uint64_t)(uint32_t)s << 20) | (uint64_t)(uint32_t)e;
                }
            }
        }
        __syncthreads();
        int n = sN < HCAP ? sN : HCAP;
        if (tid == 0) hcnt[bx] = n;
        if (tid < n) hbuf[bx*HCAP + tid] = sHit[tid];
        return;
    }
    if (bx < NREG + TRB){
        int b2 = bx - NREG;
        int kt = b2 % 104, jt = (b2 / 104) & 3, br = b2 / 416;
        const float* basis = br ? bs : bm;
        const float* root  = br ? rs : rm;
        const float* bias  = br ? qs : qm;
        unsigned short* bt = br ? bts : btm;
        int k0 = kt*32, j0 = jt*32;
        int tx = tid & 31, ty = tid >> 5;
        for (int r = ty; r < 32; r += 8)
            tile[r][tx] = bt_src(basis, root, bias, k0 + r, j0 + tx);
        __syncthreads();
        for (int r = ty; r < 32; r += 8){
            int j = j0 + r;
            if (j < 100) bt[(size_t)j*KTOT + k0 + tx] = f2b(tile[tx][r]);
        }
        return;
    }
    // chain block
    for (int i = tid; i < HASHN; i += 256){ hk[i] = -1; hv[i] = -1; }
    for (int i = tid; i < MROWS; i += 256) sIH[i] = -1;
    __syncthreads();
    for (int u = tid; u < UCNT; u += 256) hins(hk, hv, unseen_index[u], u);
    __syncthreads();
    for (int u = tid; u < UCNT; u += 256){
        int slot = hlook(hk, hv, unseen_index[u]);
        inext[u] = atomicExch(&sIH[slot], u);
    }
    __syncthreads();
    for (int i = tid; i < MROWS; i += 256) ihead[i] = sIH[i];
}

// ---- K2: build G rows (no hash): G[slot] = [ (1/cnt)*sum att⊗m | x | 1 | 0 ] bf16 ----
__global__ __launch_bounds__(256) void k_g(
        const int* __restrict__ hcnt, const uint64_t* __restrict__ hbuf,
        const int* __restrict__ eidx,
        const int* __restrict__ etype, const int* __restrict__ rel_index,
        const int* __restrict__ node_id,
        const float* __restrict__ ent, const float* __restrict__ unseen,
        const float* __restrict__ rel,
        const float* __restrict__ am, const float* __restrict__ as_,
        unsigned short* __restrict__ Gm, unsigned short* __restrict__ Gs){
    int slot = blockIdx.x;
    int tid  = threadIdx.x;
    __shared__ int sEdge[ECAP], sNE;
    __shared__ short sSrc[ECAP];
    __shared__ __align__(16) float sM[8][200];
    __shared__ __align__(16) float sAm[8][16], sAs[8][16];
    __shared__ const float* sPX[8];
    __shared__ const float* sPR[8];
    __shared__ int sT[8];

    if (tid == 0) sNE = 0;
    __syncthreads();
    // collect this slot's edges from the hit regions
    for (int r = tid; r < NREG; r += 256){
        int c = hcnt[r];
        for (int i = 0; i < c; ++i){
            uint64_t h = hbuf[r*HCAP + i];
            if ((int)((h >> 20) & 0xFFFu) == slot){
                int p = atomicAdd(&sNE, 1);
                if (p < ECAP){
                    sEdge[p] = (int)(h & 0xFFFFFu);
                    sSrc[p]  = (short)((int)(uint32_t)(h >> 32) - 1);
                }
            }
        }
    }
    __syncthreads();
    int nT = sNE;
    int nE = nT > ECAP ? ECAP : nT;

    float gm[16], gs[16];
    #pragma unroll
    for (int b = 0; b < NB; ++b){ gm[b] = 0.f; gs[b] = 0.f; }

    for (int c0 = 0; c0 < nE; c0 += 8){
        int kc = nE - c0; if (kc > 8) kc = 8;
        if (tid < kc){
            int e = sEdge[c0 + tid];
            sT[tid] = etype[e];
            int srcp = sSrc[c0 + tid];
            sPX[tid] = (srcp >= 0) ? unseen + (size_t)srcp*DE
                                   : ent + (size_t)node_id[eidx[e]]*DE;
            sPR[tid] = rel + (size_t)rel_index[e]*DE;
        }
        __syncthreads();
        for (int q = tid; q < kc*50; q += 256){
            int eL = q / 50, s = q % 50;
            const float* base = (s < 25) ? sPX[eL] : sPR[eL];
            int off = (s < 25) ? s*4 : (s-25)*4;
            float4 v = *(const float4*)(base + off);
            int kb = (s < 25) ? s*4 : (s-25)*4 + 100;
            *(float4*)&sM[eL][kb] = v;
        }
        if (tid < kc*16){
            int eL = tid >> 4, b = tid & 15;
            int t = sT[eL];
            sAm[eL][b] = am[t*NB + b];
            sAs[eL][b] = as_[t*NB + b];
        }
        __syncthreads();
        if (tid < 200){
            for (int e = 0; e < kc; ++e){
                float mk = sM[e][tid];
                const float4* pa = (const float4*)&sAm[e][0];
                const float4* ps = (const float4*)&sAs[e][0];
                #pragma unroll
                for (int q = 0; q < 4; ++q){
                    float4 va = pa[q], vs = ps[q];
                    gm[q*4+0] += va.x*mk; gm[q*4+1] += va.y*mk;
                    gm[q*4+2] += va.z*mk; gm[q*4+3] += va.w*mk;
                    gs[q*4+0] += vs.x*mk; gs[q*4+1] += vs.y*mk;
                    gs[q*4+2] += vs.z*mk; gs[q*4+3] += vs.w*mk;
                }
            }
        }
        __syncthreads();
    }
    size_t row = (size_t)slot * KTOT;
    float inv = 1.f / fmaxf((float)nT, 1.f);
    if (tid < 200){
        #pragma unroll
        for (int b = 0; b < NB; ++b){
            Gm[row + b*200 + tid] = f2b(gm[b] * inv);
            Gs[row + b*200 + tid] = f2b(gs[b] * inv);
        }
    }
    if (tid < 100){
        float xv = (slot < UCNT) ? unseen[(size_t)slot*DE + tid] : 0.f;
        unsigned short h = f2b(xv);
        Gm[row + 3200 + tid] = h; Gs[row + 3200 + tid] = h;
    } else if (tid == 100){
        Gm[row + 3300] = f2b(1.f); Gs[row + 3300] = f2b(1.f);
    } else if (tid > 100 && tid < 128){
        Gm[row + 3200 + tid] = 0; Gs[row + 3200 + tid] = 0;   // 3301..3327
    }
}

// ---- K3: out = G_aug @ B_aug. Block = (br, m16, jt); 8 waves K-split (13 chunks),
//      REGISTER-PREFETCH all 26 fragments, then MFMA chain; LDS reduce; direct
//      chain-scatter to the 3 output blocks. ----
__global__ __launch_bounds__(512) void k_gemm(
        const unsigned short* __restrict__ Gm, const unsigned short* __restrict__ Gs,
        const unsigned short* __restrict__ Btm, const unsigned short* __restrict__ Bts,
        const int* __restrict__ ihead, const int* __restrict__ inext,
        float* __restrict__ out){
    __shared__ f32x4 red[512];
    int bid = blockIdx.x;                 // 0..447
    int br  = bid / 224;
    int w2  = bid % 224;
    int m16 = w2 & 31;                    // 32 M-tiles of 16 rows
    int jt  = w2 >> 5;                    // 7 j-tiles
    int wv  = threadIdx.x >> 6;           // k-chunk 0..7
    int lane = threadIdx.x & 63;
    const unsigned short* A  = br ? Gs : Gm;
    const unsigned short* Bt = br ? Bts : Btm;
    int rowa = lane & 15, ko = (lane >> 4) * 8;
    int j0 = (jt == 6) ? 84 : jt*16;      // overlap trick, guard col>=96
    int col = j0 + rowa;
    const unsigned short* ap = A  + (size_t)(m16*16 + rowa)*KTOT + ko + wv*416;
    const unsigned short* bp = Bt + (size_t)col*KTOT + ko + wv*416;
    // prefetch ALL fragments into registers (one latency exposure, not 13)
    short8 avs[13], bvs[13];
    #pragma unroll
    for (int kc = 0; kc < 13; ++kc){
        avs[kc] = *(const short8*)(ap + kc*32);
        bvs[kc] = *(const short8*)(bp + kc*32);
    }
    f32x4 acc = {0.f, 0.f, 0.f, 0.f};
    #pragma unroll
    for (int kc = 0; kc < 13; ++kc)
        acc = __builtin_amdgcn_mfma_f32_16x16x32_bf16(avs[kc], bvs[kc], acc, 0, 0, 0);
    red[threadIdx.x] = acc;
    __syncthreads();
    if (threadIdx.x < 64){                // wave 0: reduce + epilogue
        #pragma unroll
        for (int w = 1; w < 8; ++w){
            f32x4 o = red[threadIdx.x + w*64];
            acc[0] += o[0]; acc[1] += o[1]; acc[2] += o[2]; acc[3] += o[3];
        }
        if (jt < 6 || col >= 96){
            int r0 = m16*16 + (lane >> 4)*4;
            #pragma unroll
            for (int r = 0; r < 4; ++r){
                int u = ihead[r0 + r];
                while (u >= 0){
                    if (br == 0){
                        out[(size_t)u*100 + col] = acc[r];
                        out[(size_t)(UCNT + u)*100 + col] = acc[r];
                    } else {
                        out[(size_t)(2*UCNT + u)*100 + col] = acc[r];
                    }
                    u = inext[u];
                }
            }
        }
    }
}

extern "C" void kernel_launch(void* const* d_in, const int* in_sizes, int n_in,
                              void* d_out, int out_size, void* d_ws, size_t ws_size,
                              hipStream_t stream){
    const float* ent        = (const float*)d_in[0];
    const float* rel_table  = (const float*)d_in[1];
    const float* unseen_emb = (const float*)d_in[2];
    const float* att_mu     = (const float*)d_in[3];
    const float* basis_mu   = (const float*)d_in[4];
    const float* root_mu    = (const float*)d_in[5];
    const float* bias_mu    = (const float*)d_in[6];
    const float* att_sig    = (const float*)d_in[7];
    const float* basis_sig  = (const float*)d_in[8];
    const float* root_sig   = (const float*)d_in[9];
    const float* bias_sig   = (const float*)d_in[10];
    const int* node_id      = (const int*)d_in[11];
    const int* edge_index   = (const int*)d_in[12];
    const int* edge_type    = (const int*)d_in[13];
    const int* rel_index    = (const int*)d_in[14];
    const int* unseen_index = (const int*)d_in[15];
    float* out = (float*)d_out;
    char* ws = (char*)d_ws;

    int* hcnt       = (int*)(ws + OFF_HCNT);
    int* ihead      = (int*)(ws + OFF_IHEA);
    int* inext      = (int*)(ws + OFF_INEX);
    uint64_t* hbuf  = (uint64_t*)(ws + OFF_HBUF);
    unsigned short* Gm  = (unsigned short*)(ws + OFF_GM);
    unsigned short* Gs  = (unsigned short*)(ws + OFF_GS);
    unsigned short* Btm = (unsigned short*)(ws + OFF_BTM);
    unsigned short* Bts = (unsigned short*)(ws + OFF_BTS);

    k1<<<NREG + TRB + 1, 256, 0, stream>>>(unseen_index, edge_index,
        hcnt, hbuf, ihead, inext,
        basis_mu, basis_sig, root_mu, root_sig, bias_mu, bias_sig, Btm, Bts);
    k_g<<<MROWS, 256, 0, stream>>>(hcnt, hbuf, edge_index, edge_type,
        rel_index, node_id, ent, unseen_emb, rel_table, att_mu, att_sig, Gm, Gs);
    k_gemm<<<448, 512, 0, stream>>>(Gm, Gs, Btm, Bts, ihead, inext, out);
}